// Round 2
// baseline (3630.618 us; speedup 1.0000x reference)
//
#include <hip/hip_runtime.h>

#pragma clang fp contract(off)

#define NBOX 4096
#define MBOX 256
#define NBATCH 32
#define GEPS 1e-7f
#define THREADS 512
#define NWAVES 8
#define RPT (NBOX / THREADS)   // 8 rowmax entries per thread

// ~47.5 KB LDS per block
struct SMem {
  unsigned long long rowmax[NBOX];      // (valbits<<21)|((4096-r)<<8)|(255-col); 0 = removed row
  float4 g[MBOX];                       // gt boxes
  float garea[MBOX];
  unsigned char colact[MBOX];
  unsigned short wl[NWAVES][THREADS];   // per-wave worklists (cap 512 = 64 lanes * 8 entries)
  unsigned short mi[MBOX], mj[MBOX];
  unsigned long long warpmax[NWAVES];
  int wlcnt[NWAVES];
  float redA[NWAVES], redB[NWAVES];
};

__device__ __forceinline__ unsigned long long shflxor_u64(unsigned long long x, int m) {
  unsigned int lo = (unsigned int)x;
  unsigned int hi = (unsigned int)(x >> 32);
  lo = __shfl_xor(lo, m, 64);
  hi = __shfl_xor(hi, m, 64);
  return ((unsigned long long)hi << 32) | (unsigned long long)lo;
}

// torchvision generalized_box_iou_loss, elementwise (matches reference op order)
__device__ __forceinline__ float giou_loss(float ax1, float ay1, float ax2, float ay2,
                                           float bx1, float by1, float bx2, float by2) {
  #pragma clang fp contract(off)
  float xi1 = fmaxf(ax1, bx1), yi1 = fmaxf(ay1, by1);
  float xi2 = fminf(ax2, bx2), yi2 = fminf(ay2, by2);
  float inter = fmaxf(xi2 - xi1, 0.0f) * fmaxf(yi2 - yi1, 0.0f);
  float area1 = (ax2 - ax1) * (ay2 - ay1);
  float area2 = (bx2 - bx1) * (by2 - by1);
  float uni = (area1 + area2) - inter;
  float iou = inter / (uni + GEPS);
  float xc1 = fminf(ax1, bx1), yc1 = fminf(ay1, by1);
  float xc2 = fmaxf(ax2, bx2), yc2 = fmaxf(ay2, by2);
  float areac = (xc2 - xc1) * (yc2 - yc1);
  float giou = iou - (areac - uni) / (areac + GEPS);
  return 1.0f - giou;
}

// IoU packed key for one (row box, col) pair: (valbits<<8)|(255-c)
__device__ __forceinline__ unsigned long long iou_key(const float4& a, float areaA,
                                                      const SMem& sm, int c) {
  #pragma clang fp contract(off)
  float4 g = sm.g[c];
  float w = fminf(a.z, g.z) - fmaxf(a.x, g.x);
  float h = fminf(a.w, g.w) - fmaxf(a.y, g.y);
  w = fmaxf(w, 0.0f);
  h = fmaxf(h, 0.0f);
  float inter = w * h;
  float uni = (areaA + sm.garea[c]) - inter;
  float v = inter / uni;  // IoU in [0,1]: float bits are order-preserving
  return ((unsigned long long)__float_as_uint(v) << 8) | (unsigned long long)(255 - c);
}

__device__ __forceinline__ unsigned long long pack_row(unsigned long long best, int r) {
  return ((best >> 8) << 21) | ((unsigned long long)(NBOX - r) << 8) | (best & 0xFFull);
}

// Wave recomputes up to 4 rows concurrently: 16 lanes per row, 16 cols per lane.
__device__ __forceinline__ void recompute_rows(int wid, int lane, int cnt,
                                               const float4* __restrict__ prb, SMem& sm) {
  const int cl = lane & 15;
  for (int base = 0; base < cnt; base += 4) {
    int idx = base + (lane >> 4);
    bool act = idx < cnt;
    int r = act ? (int)sm.wl[wid][idx] : 0;
    float4 a = prb[r];
    float areaA = (a.z - a.x) * (a.w - a.y);
    unsigned long long best = 0ull;
    #pragma unroll
    for (int t = 0; t < 16; ++t) {
      int c = cl + 16 * t;
      if (sm.colact[c]) {
        unsigned long long p = iou_key(a, areaA, sm, c);
        if (p > best) best = p;
      }
    }
    #pragma unroll
    for (int o = 8; o; o >>= 1) {
      unsigned long long q = shflxor_u64(best, o);
      if (q > best) best = q;
    }
    if (act && cl == 0) sm.rowmax[r] = pack_row(best, r);
  }
}

__global__ __launch_bounds__(THREADS) void match_loss_kernel(
    const float4* __restrict__ pr, const float4* __restrict__ gt,
    float* __restrict__ partial) {
  __shared__ SMem sm;
  const int b = blockIdx.x;
  const int tid = threadIdx.x;
  const int lane = tid & 63;
  const int wid = tid >> 6;
  const float4* prb = pr + (size_t)b * NBOX;
  const float4* gtb = gt + (size_t)b * MBOX;

  // stage gt boxes + areas + active flags
  if (tid < MBOX) {
    float4 g = gtb[tid];
    sm.g[tid] = g;
    sm.garea[tid] = (g.z - g.x) * (g.w - g.y);
    sm.colact[tid] = 1;
  }
  if (lane == 0) sm.wlcnt[wid] = 0;
  __syncthreads();

  // init: each thread serially computes 8 rows' maxima; fold in negative-branch loss
  float negdiff = 0.0f;
  #pragma unroll
  for (int k = 0; k < RPT; ++k) {
    int r = tid + k * THREADS;
    float4 a = prb[r];
    float areaA = (a.z - a.x) * (a.w - a.y);
    unsigned long long best = 0ull;
    #pragma unroll 4
    for (int c = 0; c < MBOX; ++c) {
      unsigned long long p = iou_key(a, areaA, sm, c);
      if (p > best) best = p;
    }
    sm.rowmax[r] = pack_row(best, r);
    negdiff += giou_loss(a.x, a.y, a.z, a.w, 0.0f, 0.0f, 0.0f, 0.0f);
  }
  __syncthreads();

  // greedy matching: 256 sequential selections, 2 barriers per step
  for (int s = 0; s < MBOX; ++s) {
    // phase 1: scan own 8 entries (kept in regs), wave shuffle-reduce
    unsigned long long m[RPT];
    unsigned long long best = 0ull;
    #pragma unroll
    for (int k = 0; k < RPT; ++k) {
      m[k] = sm.rowmax[tid + k * THREADS];
      if (m[k] > best) best = m[k];
    }
    #pragma unroll
    for (int o = 32; o; o >>= 1) {
      unsigned long long q = shflxor_u64(best, o);
      if (q > best) best = q;
    }
    if (lane == 0) sm.warpmax[wid] = best;
    __syncthreads();  // B1

    // phase 2: every thread reduces the 8 wave maxima locally (broadcast reads)
    unsigned long long selv = sm.warpmax[0];
    #pragma unroll
    for (int w = 1; w < NWAVES; ++w) {
      unsigned long long q = sm.warpmax[w];
      if (q > selv) selv = q;
    }
    const int i = NBOX - (int)((selv >> 8) & 0x1FFFull);
    const int j = 255 - (int)(selv & 0xFFull);
    if (tid == 0) { sm.mi[s] = (unsigned short)i; sm.mj[s] = (unsigned short)j; sm.rowmax[i] = 0ull; }
    // every wave writes colact[j]=0 itself: same-wave program order makes it
    // visible to this wave's recompute without a barrier (benign same-value race)
    if (lane == 0) { sm.colact[j] = 0; sm.wlcnt[wid] = 0; }
    if (s == MBOX - 1) break;

    // detection from the registers we already hold: rows whose argmax col was removed
    #pragma unroll
    for (int k = 0; k < RPT; ++k) {
      int r = tid + k * THREADS;
      if (m[k] != 0ull && (m[k] & 0xFFull) == (selv & 0xFFull) && r != i) {
        int x = atomicAdd(&sm.wlcnt[wid], 1);
        sm.wl[wid][x] = (unsigned short)r;
      }
    }
    // same-wave recompute (LDS ops within a wave are ordered; no barrier needed)
    int cnt = sm.wlcnt[wid];
    recompute_rows(wid, lane, cnt, prb, sm);
    __syncthreads();  // B2
  }
  __syncthreads();

  // losses: matched pairs + (sum_all - sum_matched)/3840 for unmatched
  float possum = 0.0f;
  if (tid < MBOX) {
    int ii = sm.mi[tid], jj = sm.mj[tid];
    float4 a = prb[ii];
    float4 g = sm.g[jj];
    possum = giou_loss(a.x, a.y, a.z, a.w, g.x, g.y, g.z, g.w);
    negdiff -= giou_loss(a.x, a.y, a.z, a.w, 0.0f, 0.0f, 0.0f, 0.0f);
  }
  #pragma unroll
  for (int o = 32; o; o >>= 1) {
    possum  += __shfl_xor(possum, o, 64);
    negdiff += __shfl_xor(negdiff, o, 64);
  }
  if (lane == 0) { sm.redA[wid] = possum; sm.redB[wid] = negdiff; }
  __syncthreads();
  if (tid == 0) {
    float pa = 0.0f, nd = 0.0f;
    for (int w = 0; w < NWAVES; ++w) { pa += sm.redA[w]; nd += sm.redB[w]; }
    partial[b] = pa / 256.0f + nd / 3840.0f;
  }
}

__global__ void finalize_kernel(const float* __restrict__ partial, float* __restrict__ out) {
  if (threadIdx.x == 0) {
    float s = 0.0f;
    for (int i = 0; i < NBATCH; ++i) s += partial[i];
    out[0] = s / 64.0f;  // /count(=32)/2
  }
}

extern "C" void kernel_launch(void* const* d_in, const int* in_sizes, int n_in,
                              void* d_out, int out_size, void* d_ws, size_t ws_size,
                              hipStream_t stream) {
  (void)in_sizes; (void)n_in; (void)out_size; (void)ws_size;
  const float4* pr = (const float4*)d_in[0];
  const float4* gt = (const float4*)d_in[1];
  float* partial = (float*)d_ws;
  float* out = (float*)d_out;
  hipLaunchKernelGGL(match_loss_kernel, dim3(NBATCH), dim3(THREADS), 0, stream, pr, gt, partial);
  hipLaunchKernelGGL(finalize_kernel, dim3(1), dim3(64), 0, stream, partial, out);
}

// Round 3
// 430.366 us; speedup vs baseline: 8.4361x; 8.4361x over previous
//
#include <hip/hip_runtime.h>

#pragma clang fp contract(off)

#define NBOX 4096
#define MBOX 256
#define NBATCH 32
#define GEPS 1e-7f
#define ISLICES 16                 // init blocks per batch
#define IROWS (NBOX / ISLICES)     // 256 rows per init block
#define MT 1024
#define MW 16

typedef unsigned long long u64;
typedef unsigned int u32;
typedef unsigned short u16;

// ws layout (bytes)
#define WS_ROWMAX 0
#define WS_COLMAX (NBATCH * NBOX * 8)                       // 1048576
#define WS_NEGPART (WS_COLMAX + NBATCH * MBOX * 8)          // +65536
#define WS_PARTIAL (WS_NEGPART + NBATCH * ISLICES * 4)      // +2048

__device__ __forceinline__ u64 shflxor_u64(u64 x, int m) {
  u32 lo = (u32)x, hi = (u32)(x >> 32);
  lo = __shfl_xor(lo, m, 64);
  hi = __shfl_xor(hi, m, 64);
  return ((u64)hi << 32) | (u64)lo;
}

// exact IEEE div, contract off -> bitwise identical everywhere it's computed
__device__ __forceinline__ u32 iou_bits(float4 a, float areaA, float4 g, float gar) {
  #pragma clang fp contract(off)
  float w = fminf(a.z, g.z) - fmaxf(a.x, g.x);
  float h = fminf(a.w, g.w) - fmaxf(a.y, g.y);
  w = fmaxf(w, 0.0f);
  h = fmaxf(h, 0.0f);
  float inter = w * h;
  float uni = (areaA + gar) - inter;   // matches (area_a + area_b) - inter
  float v = inter / uni;               // IoU >= 0: bits order-preserving
  return __float_as_uint(v);
}

__device__ __forceinline__ float giou_loss(float ax1, float ay1, float ax2, float ay2,
                                           float bx1, float by1, float bx2, float by2) {
  #pragma clang fp contract(off)
  float xi1 = fmaxf(ax1, bx1), yi1 = fmaxf(ay1, by1);
  float xi2 = fminf(ax2, bx2), yi2 = fminf(ay2, by2);
  float inter = fmaxf(xi2 - xi1, 0.0f) * fmaxf(yi2 - yi1, 0.0f);
  float area1 = (ax2 - ax1) * (ay2 - ay1);
  float area2 = (bx2 - bx1) * (by2 - by1);
  float uni = (area1 + area2) - inter;
  float iou = inter / (uni + GEPS);
  float xc1 = fminf(ax1, bx1), yc1 = fminf(ay1, by1);
  float xc2 = fmaxf(ax2, bx2), yc2 = fmaxf(ay2, by2);
  float areac = (xc2 - xc1) * (yc2 - yc1);
  float giou = iou - (areac - uni) / (areac + GEPS);
  return 1.0f - giou;
}

// key: (iou_bits<<22) | ((4096-row)<<9) | (256-col); 0 = removed/empty.
// u64 max == (value desc, row asc, col asc) == jnp.argmax flat-index tie-break.

__global__ __launch_bounds__(1024) void init_kernel(
    const float4* __restrict__ pr, const float4* __restrict__ gt,
    u64* __restrict__ rowmaxG, u64* __restrict__ colmaxG, float* __restrict__ negpart) {
  __shared__ float4 g[MBOX];
  __shared__ float garea[MBOX];
  __shared__ u64 colmaxL[MBOX];
  __shared__ float red[16];
  const int blk = blockIdx.x;
  const int b = blk >> 4, s = blk & 15;
  const int tid = threadIdx.x;
  const int lane = tid & 63, wid = tid >> 6;
  const float4* prb = pr + (size_t)b * NBOX;

  if (tid < MBOX) {
    float4 gg = gt[(size_t)b * MBOX + tid];
    g[tid] = gg;
    garea[tid] = (gg.z - gg.x) * (gg.w - gg.y);
    colmaxL[tid] = 0ull;
  }
  __syncthreads();

  const int r0 = s * IROWS;
  // row pass: 4 threads per row, 64 cols each
  const int rr = tid >> 2, quad = tid & 3;
  const int r = r0 + rr;
  float4 a = prb[r];
  float areaA = (a.z - a.x) * (a.w - a.y);
  u64 best = 0ull;  // (val<<9)|(256-c)
  for (int k = 0; k < 64; ++k) {
    int c = quad * 64 + k;
    u64 p = ((u64)iou_bits(a, areaA, g[c], garea[c]) << 9) | (u64)(MBOX - c);
    if (p > best) best = p;
  }
  #pragma unroll
  for (int o = 1; o < 4; o <<= 1) {
    u64 q = shflxor_u64(best, o);
    if (q > best) best = q;
  }
  float nd = 0.0f;
  if (quad == 0) {
    rowmaxG[(size_t)b * NBOX + r] =
        ((best >> 9) << 22) | ((u64)(NBOX - r) << 9) | (best & 0x1FFull);
    nd = giou_loss(a.x, a.y, a.z, a.w, 0.0f, 0.0f, 0.0f, 0.0f);
  }

  // col pass: thread = (quarter q, col j); 64 rows each; local max then 1 LDS atomic
  const int j = tid & 255, qq = tid >> 8;
  float4 gb = g[j];
  float gar = garea[j];
  u64 cbest = 0ull;  // (val<<13)|(4096-r)
  for (int k = 0; k < 64; ++k) {
    int r2 = r0 + qq * 64 + k;
    float4 a2 = prb[r2];
    float ar2 = (a2.z - a2.x) * (a2.w - a2.y);
    u64 p = ((u64)iou_bits(a2, ar2, gb, gar) << 13) | (u64)(NBOX - r2);
    if (p > cbest) cbest = p;
  }
  atomicMax(&colmaxL[j], cbest);
  __syncthreads();
  if (tid < MBOX) {
    u64 cb = colmaxL[tid];
    u64 packed = ((cb >> 13) << 22) | ((cb & 0x1FFFull) << 9) | (u64)(MBOX - tid);
    atomicMax(&colmaxG[(size_t)b * MBOX + tid], packed);
  }

  // negdiff partial (deterministic per-block)
  #pragma unroll
  for (int o = 32; o; o >>= 1) nd += __shfl_xor(nd, o, 64);
  if (lane == 0) red[wid] = nd;
  __syncthreads();
  if (tid == 0) {
    float t = 0.0f;
    for (int w = 0; w < 16; ++w) t += red[w];
    negpart[blk] = t;
  }
}

__global__ __launch_bounds__(MT) void match_kernel(
    const float4* __restrict__ pr, const float4* __restrict__ gt,
    const u64* __restrict__ rowmaxG, const u64* __restrict__ colmaxG,
    const float* __restrict__ negpart, float* __restrict__ partial) {
  __shared__ u64 rowmax[NBOX];        // 32 KB
  __shared__ u64 colmax[MBOX];        // 2 KB
  __shared__ float4 g[MBOX];          // 4 KB
  __shared__ float garea[MBOX];       // 1 KB
  __shared__ unsigned char colact[MBOX];
  __shared__ u16 wl[MW][256];         // 8 KB (cap: 64 lanes * 4 rows)
  __shared__ u16 colwl[MBOX];
  __shared__ int wlcnt[MW];
  __shared__ int colcnt;
  __shared__ int nmatch;
  __shared__ float redA[MW], redB[MW];

  const int b = blockIdx.x, tid = threadIdx.x;
  const int lane = tid & 63, wid = tid >> 6;
  const float4* prb = pr + (size_t)b * NBOX;

  for (int k = tid; k < NBOX; k += MT) rowmax[k] = rowmaxG[(size_t)b * NBOX + k];
  if (tid < MBOX) {
    float4 gg = gt[(size_t)b * MBOX + tid];
    g[tid] = gg;
    garea[tid] = (gg.z - gg.x) * (gg.w - gg.y);
    colmax[tid] = colmaxG[(size_t)b * MBOX + tid];
    colact[tid] = 1;
  }
  if (tid == 0) { nmatch = 0; colcnt = 0; }
  if (lane == 0) wlcnt[wid] = 0;
  __syncthreads();

  float possum = 0.0f, negsub = 0.0f;

  for (int round = 0; round < MBOX; ++round) {
    // P1: per active col, dominant-pair test (2 dependent LDS reads)
    if (tid < MBOX && colact[tid]) {
      u64 cm = colmax[tid];
      int i = NBOX - (int)((cm >> 9) & 0x1FFFull);
      u64 rm = rowmax[i];
      if ((rm & 0x1FFull) == (u64)(MBOX - tid)) {
        colact[tid] = 0;
        rowmax[i] = 0ull;
        colmax[tid] = 0ull;
        float4 a = prb[i];
        float4 gg = g[tid];
        possum += giou_loss(a.x, a.y, a.z, a.w, gg.x, gg.y, gg.z, gg.w);
        negsub += giou_loss(a.x, a.y, a.z, a.w, 0.0f, 0.0f, 0.0f, 0.0f);
        atomicAdd(&nmatch, 1);
      }
    }
    __syncthreads();  // B1
    if (nmatch >= MBOX) break;

    // P2: detect invalidations
    #pragma unroll
    for (int k = 0; k < NBOX / MT; ++k) {
      int r = tid + k * MT;
      u64 rm = rowmax[r];
      if (rm != 0ull) {
        int ac = MBOX - (int)(rm & 0x1FFull);
        if (!colact[ac]) {
          int x = atomicAdd(&wlcnt[wid], 1);
          wl[wid][x] = (u16)r;
        }
      }
    }
    if (tid < MBOX && colact[tid]) {
      u64 cm = colmax[tid];
      int i = NBOX - (int)((cm >> 9) & 0x1FFFull);
      if (rowmax[i] == 0ull) {
        int x = atomicAdd(&colcnt, 1);
        colwl[x] = (u16)tid;
      }
    }
    __syncthreads();  // B2

    // P3a: row recomputes (per-wave list; 4 rows x 16 lanes)
    int rcnt = wlcnt[wid];
    for (int base = 0; base < rcnt; base += 4) {
      int idx = base + (lane >> 4);
      bool act = idx < rcnt;
      int r = act ? (int)wl[wid][idx] : 0;
      float4 a = prb[r];
      float areaA = (a.z - a.x) * (a.w - a.y);
      int cl = lane & 15;
      u64 best = 0ull;
      #pragma unroll
      for (int t = 0; t < 16; ++t) {
        int c = cl + 16 * t;
        if (colact[c]) {
          u64 p = ((u64)iou_bits(a, areaA, g[c], garea[c]) << 9) | (u64)(MBOX - c);
          if (p > best) best = p;
        }
      }
      #pragma unroll
      for (int o = 8; o; o >>= 1) {
        u64 q = shflxor_u64(best, o);
        if (q > best) best = q;
      }
      if (act && cl == 0)
        rowmax[r] = ((best >> 9) << 22) | ((u64)(NBOX - r) << 9) | (best & 0x1FFull);
    }
    // P3b: col rescans (wave per col; rowmax[r]!=0 used only as activity flag)
    int ccnt = colcnt;
    for (int x = wid; x < ccnt; x += MW) {
      int j = (int)colwl[x];
      float4 gb = g[j];
      float gar = garea[j];
      u64 best = 0ull;
      for (int t = 0; t < NBOX / 64; ++t) {
        int r = lane + 64 * t;
        if (rowmax[r] != 0ull) {
          float4 a = prb[r];
          float areaA = (a.z - a.x) * (a.w - a.y);
          u64 p = ((u64)iou_bits(a, areaA, gb, gar) << 13) | (u64)(NBOX - r);
          if (p > best) best = p;
        }
      }
      #pragma unroll
      for (int o = 32; o; o >>= 1) {
        u64 q = shflxor_u64(best, o);
        if (q > best) best = q;
      }
      if (lane == 0)
        colmax[j] = ((best >> 13) << 22) | ((best & 0x1FFFull) << 9) | (u64)(MBOX - j);
    }
    __syncthreads();  // B3
    if (lane == 0) wlcnt[wid] = 0;
    if (tid == 0) colcnt = 0;
    // next P1 doesn't touch counters; B1 publishes resets before next P2
  }

  // final reduce: possum/256 + (negG - negsub)/3840
  #pragma unroll
  for (int o = 32; o; o >>= 1) {
    possum += __shfl_xor(possum, o, 64);
    negsub += __shfl_xor(negsub, o, 64);
  }
  if (lane == 0) { redA[wid] = possum; redB[wid] = negsub; }
  __syncthreads();
  if (tid == 0) {
    float pa = 0.0f, ns = 0.0f;
    for (int w = 0; w < MW; ++w) { pa += redA[w]; ns += redB[w]; }
    float ng = 0.0f;
    for (int s = 0; s < ISLICES; ++s) ng += negpart[b * ISLICES + s];
    partial[b] = pa / 256.0f + (ng - ns) / 3840.0f;
  }
}

__global__ void finalize_kernel(const float* __restrict__ partial, float* __restrict__ out) {
  if (threadIdx.x == 0) {
    float s = 0.0f;
    for (int i = 0; i < NBATCH; ++i) s += partial[i];
    out[0] = s / 64.0f;  // /count(=32)/2
  }
}

extern "C" void kernel_launch(void* const* d_in, const int* in_sizes, int n_in,
                              void* d_out, int out_size, void* d_ws, size_t ws_size,
                              hipStream_t stream) {
  (void)in_sizes; (void)n_in; (void)out_size; (void)ws_size;
  const float4* pr = (const float4*)d_in[0];
  const float4* gt = (const float4*)d_in[1];
  char* ws = (char*)d_ws;
  u64* rowmaxG = (u64*)(ws + WS_ROWMAX);
  u64* colmaxG = (u64*)(ws + WS_COLMAX);
  float* negpart = (float*)(ws + WS_NEGPART);
  float* partial = (float*)(ws + WS_PARTIAL);
  float* out = (float*)d_out;

  hipMemsetAsync(colmaxG, 0, NBATCH * MBOX * 8, stream);  // atomicMax target must start at 0
  hipLaunchKernelGGL(init_kernel, dim3(NBATCH * ISLICES), dim3(1024), 0, stream,
                     pr, gt, rowmaxG, colmaxG, negpart);
  hipLaunchKernelGGL(match_kernel, dim3(NBATCH), dim3(MT), 0, stream,
                     pr, gt, rowmaxG, colmaxG, negpart, partial);
  hipLaunchKernelGGL(finalize_kernel, dim3(1), dim3(64), 0, stream, partial, out);
}